// Round 18
// baseline (117.155 us; speedup 1.0000x reference)
//
#include <hip/hip_runtime.h>

#define N_ROWS 8192
#define IN_DIM 1024
#define KF     8

typedef _Float16 half8 __attribute__((ext_vector_type(8)));
typedef _Float16 half4 __attribute__((ext_vector_type(4)));
typedef float    floatx4 __attribute__((ext_vector_type(4)));
typedef float    floatx16 __attribute__((ext_vector_type(16)));

__device__ __forceinline__ half8 ld_half8(const _Float16* p) {
    int4 t = *(const int4*)p;
    return __builtin_bit_cast(half8, t);
}
__device__ __forceinline__ void fsplit(float v, _Float16& h, _Float16& l) {
    _Float16 x = (_Float16)v;
    h = x;
    l = (_Float16)((v - (float)x) * 2048.0f);
}
__device__ __forceinline__ void gload16(const void* g, void* l) {
    __builtin_amdgcn_global_load_lds(
        (const __attribute__((address_space(1))) void*)g,
        (__attribute__((address_space(3))) void*)l,
        16, 0, 0);
}

// ---------------------------------------------------------------------------
// prepW: y = role: 0 split E, 1 split W2, 2 transp W1, 3 transp W3, 4 zero Mcnt
__global__ __launch_bounds__(256) void prepW(
        const float* __restrict__ emb, const float* __restrict__ W1,
        const float* __restrict__ W2, const float* __restrict__ W3,
        float* __restrict__ Mcnt,
        _Float16* __restrict__ Eh, _Float16* __restrict__ El,
        _Float16* __restrict__ W1th, _Float16* __restrict__ W1tl,
        _Float16* __restrict__ W2h, _Float16* __restrict__ W2l,
        _Float16* __restrict__ W3th, _Float16* __restrict__ W3tl) {
    const int task = blockIdx.y;
    const int bx   = blockIdx.x;

    if (task == 4) {           // zero Mcnt (4 MB)
        size_t i = ((size_t)bx * 256 + threadIdx.x) << 2;
        floatx4 z = {0.f, 0.f, 0.f, 0.f};
        *(floatx4*)&Mcnt[i] = z;
        return;
    }
    if (task <= 1) {           // natural split (proven)
        const float* S = task ? W2 : emb;
        _Float16* Hp = task ? W2h : Eh;
        _Float16* Lp = task ? W2l : El;
        size_t i = ((size_t)bx * 256 + threadIdx.x) << 2;
        float4 v = *(const float4*)&S[i];
        float vv[4] = {v.x, v.y, v.z, v.w};
        half4 h, l;
        #pragma unroll
        for (int j = 0; j < 4; ++j) { _Float16 hh, ll; fsplit(vv[j], hh, ll); h[j] = hh; l[j] = ll; }
        *(int2*)&Hp[i] = __builtin_bit_cast(int2, h);
        *(int2*)&Lp[i] = __builtin_bit_cast(int2, l);
        return;
    }
    if (bx >= 256) return;     // transposed split (proven)
    const float* S = (task == 3) ? W3 : W1;
    _Float16* Hp = (task == 3) ? W3th : W1th;
    _Float16* Lp = (task == 3) ? W3tl : W1tl;
    __shared__ float sh[64][65];
    const int r0 = (bx >> 4) << 6, c0 = (bx & 15) << 6;
    #pragma unroll
    for (int it = 0; it < 4; ++it) {
        int r = (threadIdx.x >> 4) + (it << 4);
        int c = (threadIdx.x & 15) << 2;
        float4 v = *(const float4*)&S[(size_t)(r0 + r) * 1024 + c0 + c];
        sh[r][c] = v.x; sh[r][c + 1] = v.y; sh[r][c + 2] = v.z; sh[r][c + 3] = v.w;
    }
    __syncthreads();
    int nl = threadIdx.x >> 2;
    #pragma unroll
    for (int cc = 0; cc < 2; ++cc) {
        int kq = ((threadIdx.x & 3) << 4) + (cc << 3);
        half8 h, l;
        #pragma unroll
        for (int j = 0; j < 8; ++j) {
            _Float16 hh, ll;
            fsplit(sh[kq + j][nl], hh, ll);
            h[j] = hh; l[j] = ll;
        }
        *(int4*)&Hp[(size_t)(c0 + nl) * 1024 + r0 + kq] = __builtin_bit_cast(int4, h);
        *(int4*)&Lp[(size_t)(c0 + nl) * 1024 + r0 + kq] = __builtin_bit_cast(int4, l);
    }
}

// ---------------------------------------------------------------------------
struct GemmDesc {
    const _Float16 *Ah, *Al;
    const _Float16 *Bh, *Bl;
    float* Df;
    _Float16 *Dnh, *Dnl;
    _Float16 *Dth, *Dtl;
};

// proven split-f16 MFMA GEMM body (64x64, 4 waves, 32x32x16, 3 chains)
__device__ __forceinline__ void gemm_body(GemmDesc d, _Float16 (*lds)[4][64][64],
                                          int bx, int by) {
    const int tid  = threadIdx.x;
    const int lane = tid & 63;
    const int w    = tid >> 6;
    const int wm   = w >> 1, wn = w & 1;
    const int brow = by << 6;
    const int bcol = bx << 6;

    const _Float16* gsrc = (w == 0) ? d.Ah : (w == 1) ? d.Al : (w == 2) ? d.Bh : d.Bl;
    const int rowbase = (w < 2) ? brow : bcol;
    const int swz = (((lane & 7) ^ ((lane >> 3) & 7)) << 3);
    const _Float16* gbase = gsrc + (size_t)(rowbase + (lane >> 3)) * 1024 + swz;

#define STAGE(kt_, buf_) do {                                              \
        _Float16* lb = &lds[buf_][w][0][0];                                \
        const _Float16* gb = gbase + ((kt_) << 6);                         \
        _Pragma("unroll")                                                  \
        for (int c = 0; c < 8; ++c)                                        \
            gload16(gb + ((size_t)(c << 3) << 10), lb + (c << 9));         \
    } while (0)

    const int l31  = lane & 31;
    const int kh   = lane >> 5;
    const int arow = (wm << 5) + l31;
    const int brw  = (wn << 5) + l31;
    const int r7   = l31 & 7;

    floatx16 acc0 = {};
    floatx16 acc1 = {};
    floatx16 acc2 = {};

    STAGE(0, 0);
    __syncthreads();

    int cur = 0;
    for (int kt = 0; kt < 16; ++kt) {
        if (kt < 15) STAGE(kt + 1, cur ^ 1);
        const _Float16* pa_h = &lds[cur][0][arow][0];
        const _Float16* pa_l = &lds[cur][1][arow][0];
        const _Float16* pb_h = &lds[cur][2][brw][0];
        const _Float16* pb_l = &lds[cur][3][brw][0];
        #pragma unroll
        for (int kc = 0; kc < 4; ++kc) {
            int ca = ((((kc << 1) | kh) ^ r7) << 3);
            half8 ah = ld_half8(pa_h + ca);
            half8 al = ld_half8(pa_l + ca);
            half8 bh = ld_half8(pb_h + ca);
            half8 bl = ld_half8(pb_l + ca);
            acc0 = __builtin_amdgcn_mfma_f32_32x32x16_f16(ah, bh, acc0, 0, 0, 0);
            acc1 = __builtin_amdgcn_mfma_f32_32x32x16_f16(ah, bl, acc1, 0, 0, 0);
            acc2 = __builtin_amdgcn_mfma_f32_32x32x16_f16(al, bh, acc2, 0, 0, 0);
        }
        if (kt < 15) {
            __syncthreads();
            cur ^= 1;
        }
    }
#undef STAGE

    const float is = 1.0f / 2048.0f;
    const int grow = brow + (wm << 5) + (kh << 2);
    const int gcol = bcol + (wn << 5) + l31;

    if (d.Df) {
        #pragma unroll
        for (int r = 0; r < 16; ++r) {
            int row = grow + (r & 3) + ((r >> 2) << 3);
            d.Df[(size_t)row * 1024 + gcol] = acc0[r] + (acc1[r] + acc2[r]) * is;
        }
    }
    if (d.Dnh) {
        #pragma unroll
        for (int r = 0; r < 16; ++r) {
            int row = grow + (r & 3) + ((r >> 2) << 3);
            _Float16 h, l;
            fsplit(acc0[r] + (acc1[r] + acc2[r]) * is, h, l);
            d.Dnh[(size_t)row * 1024 + gcol] = h;
            d.Dnl[(size_t)row * 1024 + gcol] = l;
        }
    }
    if (d.Dth) {
        #pragma unroll
        for (int g = 0; g < 4; ++g) {
            half4 hv, lv;
            #pragma unroll
            for (int j = 0; j < 4; ++j) {
                int r = (g << 2) + j;
                _Float16 h, l;
                fsplit(acc0[r] + (acc1[r] + acc2[r]) * is, h, l);
                hv[j] = h; lv[j] = l;
            }
            int row = grow + (g << 3);
            *(int2*)&d.Dth[(size_t)gcol * 1024 + row] = __builtin_bit_cast(int2, hv);
            *(int2*)&d.Dtl[(size_t)gcol * 1024 + row] = __builtin_bit_cast(int2, lv);
        }
    }
}

// ---------------------------------------------------------------------------
// fused S1ab GEMM + extract: grid (20,16,2). x<16 -> GEMM tile (x=col, y=row,
// z=problem). x>=16 -> extract sub-block, 64 rows each; role interleaved on x
// so extract blocks co-reside with GEMM blocks per CU (atomic pipe || MFMA).
__global__ __launch_bounds__(256) void gemm_s1_extract(
        GemmDesc d0, GemmDesc d1,
        const int* __restrict__ x, int* __restrict__ idx, float* __restrict__ M) {
    __shared__ _Float16 lds[2][4][64][64];
    __shared__ int cols[4][KF];

    if (blockIdx.x < 16) {
        gemm_body(blockIdx.z ? d1 : d0, lds, blockIdx.x, blockIdx.y);
        return;
    }
    // extract role: 128 blocks x 64 rows
    const int eb   = ((int)blockIdx.z * 16 + (int)blockIdx.y) * 4 + ((int)blockIdx.x - 16);
    const int wv   = threadIdx.x >> 6;
    const int lane = threadIdx.x & 63;

    for (int it = 0; it < 64; it += 4) {
        const int r    = eb * 64 + it + wv;
        const int* row = x + (size_t)r * IN_DIM;

        int vals[16];
        #pragma unroll
        for (int j = 0; j < 4; ++j) {
            int4 v = ((const int4*)row)[lane * 4 + j];
            vals[j * 4 + 0] = v.x;
            vals[j * 4 + 1] = v.y;
            vals[j * 4 + 2] = v.z;
            vals[j * 4 + 3] = v.w;
        }
        int c = 0;
        #pragma unroll
        for (int j = 0; j < 16; ++j) c += (vals[j] != 0);

        int s = c;
        #pragma unroll
        for (int o = 1; o < 64; o <<= 1) {
            int t = __shfl_up(s, o, 64);
            if (lane >= o) s += t;
        }
        int pos = s - c;

        #pragma unroll
        for (int j = 0; j < 16; ++j) {
            if (vals[j] != 0) {
                int col = lane * 16 + j;
                if (pos < KF) {
                    idx[r * KF + pos] = col;
                    cols[wv][pos] = col;
                }
                pos++;
            }
        }
        __syncthreads();
        int pi = lane >> 3, pj = lane & 7;
        if (pi <= pj) {
            int ci = cols[wv][pi];
            int cj = cols[wv][pj];     // ci <= cj (ascending extraction)
            atomicAdd(&M[ci * IN_DIM + cj], 1.0f);
        }
        __syncthreads();
    }
}

// ---------------------------------------------------------------------------
// prepM4: M' = diag(wG)*(U+U^T)*diag(d) + diag(wC), split; counts = diag(U)
__global__ __launch_bounds__(256) void prepM4(const float* __restrict__ Mc,
                                              _Float16* __restrict__ Mph,
                                              _Float16* __restrict__ Mpl) {
    const int bx = blockIdx.x;
    const int i0 = (bx >> 4) << 6;
    const int j0 = (bx & 15) << 6;
    __shared__ float tU[64][65];
    __shared__ float ddi[64], ddj[64];
    #pragma unroll
    for (int it = 0; it < 4; ++it) {
        int r = (threadIdx.x >> 4) + (it << 4);
        int c = (threadIdx.x & 15) << 2;
        float4 v = *(const float4*)&Mc[(size_t)(j0 + r) * 1024 + i0 + c];
        tU[r][c] = v.x; tU[r][c + 1] = v.y; tU[r][c + 2] = v.z; tU[r][c + 3] = v.w;
    }
    if (threadIdx.x < 64) {
        int c = i0 + threadIdx.x;
        ddi[threadIdx.x] = rsqrtf(Mc[(size_t)c * 1025] + 1.0f);
    } else if (threadIdx.x < 128) {
        int t = threadIdx.x - 64;
        int c = j0 + t;
        ddj[t] = rsqrtf(Mc[(size_t)c * 1025] + 1.0f);
    }
    __syncthreads();

    const float s1 = 1.f / 3.f, s3 = 1.f / 27.f, s5 = 1.f / 243.f;
    const int ii = threadIdx.x >> 2;
    const int gi = i0 + ii;
    float dr = ddi[ii];
    float d2 = dr * dr;
    float wg = s3 * d2;
    float wc = dr * (s1 * d2 * d2 + s3 * d2 + s5);

    #pragma unroll
    for (int q = 0; q < 4; ++q) {
        int jj = ((threadIdx.x & 3) << 4) + (q << 2);
        size_t gidx = (size_t)gi * 1024 + j0 + jj;
        float4 un = *(const float4*)&Mc[gidx];
        float uv[4] = {un.x, un.y, un.z, un.w};
        half4 h, l;
        #pragma unroll
        for (int t = 0; t < 4; ++t) {
            int gj = j0 + jj + t;
            float m = (gi == gj) ? uv[t] : (uv[t] + tU[jj + t][ii]);
            float v = m * ddj[jj + t] * wg + ((gi == gj) ? wc : 0.f);
            _Float16 hh, ll;
            fsplit(v, hh, ll);
            h[t] = hh; l[t] = ll;
        }
        *(int2*)&Mph[gidx] = __builtin_bit_cast(int2, h);
        *(int2*)&Mpl[gidx] = __builtin_bit_cast(int2, l);
    }
}

// ---------------------------------------------------------------------------
// standalone GEMM wrapper (for S3)
__global__ __launch_bounds__(256) void gemm_split(GemmDesc d0, GemmDesc d1)
{
    __shared__ _Float16 lds[2][4][64][64];
    gemm_body(blockIdx.z ? d1 : d0, lds, blockIdx.x, blockIdx.y);
}

// ---------------------------------------------------------------------------
// k-split-2 GEMM, f32 partials: grid (16,16,2), z = K-half. (proven, R15)
__global__ __launch_bounds__(256) void gemm_ks2_f32(
        const _Float16* __restrict__ Ah, const _Float16* __restrict__ Al,
        const _Float16* __restrict__ Bh, const _Float16* __restrict__ Bl,
        float* __restrict__ Pp)
{
    __shared__ _Float16 lds[2][4][64][64];

    const int tid  = threadIdx.x;
    const int lane = tid & 63;
    const int w    = tid >> 6;
    const int wm   = w >> 1, wn = w & 1;
    const int brow = blockIdx.y << 6;
    const int bcol = blockIdx.x << 6;
    const int kbeg = blockIdx.z << 9;

    const _Float16* gsrc = (w == 0) ? Ah : (w == 1) ? Al : (w == 2) ? Bh : Bl;
    const int rowbase = (w < 2) ? brow : bcol;
    const int swz = (((lane & 7) ^ ((lane >> 3) & 7)) << 3);
    const _Float16* gbase = gsrc + (size_t)(rowbase + (lane >> 3)) * 1024 + kbeg + swz;

#define STAGE(kt_, buf_) do {                                              \
        _Float16* lb = &lds[buf_][w][0][0];                                \
        const _Float16* gb = gbase + ((kt_) << 6);                         \
        _Pragma("unroll")                                                  \
        for (int c = 0; c < 8; ++c)                                        \
            gload16(gb + ((size_t)(c << 3) << 10), lb + (c << 9));         \
    } while (0)

    const int l31  = lane & 31;
    const int kh   = lane >> 5;
    const int arow = (wm << 5) + l31;
    const int brw  = (wn << 5) + l31;
    const int r7   = l31 & 7;

    floatx16 acc0 = {};
    floatx16 acc1 = {};
    floatx16 acc2 = {};

    STAGE(0, 0);
    __syncthreads();

    int cur = 0;
    for (int kt = 0; kt < 8; ++kt) {
        if (kt < 7) STAGE(kt + 1, cur ^ 1);
        const _Float16* pa_h = &lds[cur][0][arow][0];
        const _Float16* pa_l = &lds[cur][1][arow][0];
        const _Float16* pb_h = &lds[cur][2][brw][0];
        const _Float16* pb_l = &lds[cur][3][brw][0];
        #pragma unroll
        for (int kc = 0; kc < 4; ++kc) {
            int ca = ((((kc << 1) | kh) ^ r7) << 3);
            half8 ah = ld_half8(pa_h + ca);
            half8 al = ld_half8(pa_l + ca);
            half8 bh = ld_half8(pb_h + ca);
            half8 bl = ld_half8(pb_l + ca);
            acc0 = __builtin_amdgcn_mfma_f32_32x32x16_f16(ah, bh, acc0, 0, 0, 0);
            acc1 = __builtin_amdgcn_mfma_f32_32x32x16_f16(ah, bl, acc1, 0, 0, 0);
            acc2 = __builtin_amdgcn_mfma_f32_32x32x16_f16(al, bh, acc2, 0, 0, 0);
        }
        if (kt < 7) {
            __syncthreads();
            cur ^= 1;
        }
    }
#undef STAGE

    const float is = 1.0f / 2048.0f;
    const int grow = brow + (wm << 5) + (kh << 2);
    const int gcol = bcol + (wn << 5) + l31;
    float* Pt = Pp + ((size_t)blockIdx.z << 20);
    #pragma unroll
    for (int r = 0; r < 16; ++r) {
        int row = grow + (r & 3) + ((r >> 2) << 3);
        Pt[(size_t)row * 1024 + gcol] = acc0[r] + (acc1[r] + acc2[r]) * is;
    }
}

// ---------------------------------------------------------------------------
// combineT: y=0 -> T = split(P0+P1); y=1 -> beta1p = b1@W23; y=2 -> beta2 = b2@W3
__global__ __launch_bounds__(256) void combineT(
        const float* __restrict__ Pp,
        _Float16* __restrict__ Th, _Float16* __restrict__ Tl,
        const _Float16* __restrict__ W23th, const _Float16* __restrict__ W23tl,
        const float* __restrict__ b1, float* __restrict__ beta1p,
        const _Float16* __restrict__ W3th, const _Float16* __restrict__ W3tl,
        const float* __restrict__ b2, float* __restrict__ beta2) {
    if (blockIdx.y == 0) {
        size_t i = ((size_t)blockIdx.x * 256 + threadIdx.x) << 2;
        float4 a = *(const float4*)&Pp[i];
        float4 b = *(const float4*)&Pp[(1 << 20) + i];
        float vv[4] = {a.x + b.x, a.y + b.y, a.z + b.z, a.w + b.w};
        half4 h, l;
        #pragma unroll
        for (int j = 0; j < 4; ++j) { _Float16 hh, ll; fsplit(vv[j], hh, ll); h[j] = hh; l[j] = ll; }
        *(int2*)&Th[i] = __builtin_bit_cast(int2, h);
        *(int2*)&Tl[i] = __builtin_bit_cast(int2, l);
        return;
    }
    const int which = blockIdx.y - 1;
    const _Float16* Wh = which ? W3th : W23th;
    const _Float16* Wl = which ? W3tl : W23tl;
    const float*    vv = which ? b2 : b1;
    float*          yy = which ? beta2 : beta1p;
    const float is = 1.0f / 2048.0f;
    int n  = blockIdx.x;
    int k0 = threadIdx.x << 2;
    int2 th = *(const int2*)&Wh[(size_t)n * 1024 + k0];
    int2 tl = *(const int2*)&Wl[(size_t)n * 1024 + k0];
    half4 h = __builtin_bit_cast(half4, th);
    half4 l = __builtin_bit_cast(half4, tl);
    float4 b = *(const float4*)&vv[k0];
    float acc = ((float)h[0] + (float)l[0] * is) * b.x
              + ((float)h[1] + (float)l[1] * is) * b.y
              + ((float)h[2] + (float)l[2] * is) * b.z
              + ((float)h[3] + (float)l[3] * is) * b.w;
    #pragma unroll
    for (int o = 1; o < 64; o <<= 1) acc += __shfl_xor(acc, o, 64);
    __shared__ float red[4];
    if ((threadIdx.x & 63) == 0) red[threadIdx.x >> 6] = acc;
    __syncthreads();
    if (threadIdx.x == 0) yy[n] = red[0] + red[1] + red[2] + red[3];
}

// ---------------------------------------------------------------------------
// out[r] = sum_i H[c_i] + g1*beta1p + g2*beta2 + b3 ; counts from diag(U)
__global__ __launch_bounds__(256) void final_out(const float* __restrict__ H,
                                                 const int* __restrict__ idx,
                                                 const float* __restrict__ Mc,
                                                 const float* __restrict__ beta1p,
                                                 const float* __restrict__ beta2,
                                                 const float* __restrict__ b3,
                                                 float* __restrict__ out) {
    const int r = blockIdx.x;
    __shared__ int   sc[KF];
    __shared__ float sd[KF];
    if (threadIdx.x < KF) {
        int c = idx[r * KF + threadIdx.x];
        sc[threadIdx.x] = c;
        sd[threadIdx.x] = rsqrtf(Mc[(size_t)c * 1025] + 1.0f);
    }
    __syncthreads();

    const float s1 = 1.f / 3.f, s2 = 1.f / 9.f, s3 = 1.f / 27.f, s4 = 1.f / 81.f;

    float p = 0.f, q = 0.f, sum2 = 0.f;
    #pragma unroll
    for (int i = 0; i < KF; ++i) {
        float dd = sd[i];
        p += dd;
        sum2 += dd * dd;
        q += dd * dd * dd;
    }
    float u  = (float)KF - sum2;
    float g1 = s2 * u + s1 * q + s3 * p + s4;
    float g2 = s1 * p + s2;

    int j = threadIdx.x << 2;
    float4 bb1 = *(const float4*)&beta1p[j];
    float4 bb2 = *(const float4*)&beta2[j];
    float4 b3v = *(const float4*)&b3[j];
    floatx4 acc;
    acc.x = g1 * bb1.x + g2 * bb2.x + b3v.x;
    acc.y = g1 * bb1.y + g2 * bb2.y + b3v.y;
    acc.z = g1 * bb1.z + g2 * bb2.z + b3v.z;
    acc.w = g1 * bb1.w + g2 * bb2.w + b3v.w;

    #pragma unroll
    for (int i = 0; i < KF; ++i) {
        float4 h = *(const float4*)&H[(size_t)sc[i] * 1024 + j];
        acc.x += h.x;
        acc.y += h.y;
        acc.z += h.z;
        acc.w += h.w;
    }
    __builtin_nontemporal_store(acc, (floatx4*)&out[(size_t)r * 1024 + j]);
}

// ---------------------------------------------------------------------------
extern "C" void kernel_launch(void* const* d_in, const int* in_sizes, int n_in,
                              void* d_out, int out_size, void* d_ws, size_t ws_size,
                              hipStream_t stream) {
    const int*   x   = (const int*)d_in[0];
    const float* emb = (const float*)d_in[1];
    const float* Ws  = (const float*)d_in[2];
    const float* bsv = (const float*)d_in[3];
    float* out = (float*)d_out;

    char* ws = (char*)d_ws;
    const size_t MB = 1 << 20;
    int*   idx    = (int*)(ws);
    float* beta1p = (float*)(ws + 0x44000);
    float* beta2  = (float*)(ws + 0x45000);
    float* Mcnt   = (float*)(ws + 1 * MB);
    _Float16* Eh    = (_Float16*)(ws + 5 * MB);
    _Float16* El    = (_Float16*)(ws + 7 * MB);
    _Float16* W1th  = (_Float16*)(ws + 9 * MB);
    _Float16* W1tl  = (_Float16*)(ws + 11 * MB);
    _Float16* W2h   = (_Float16*)(ws + 13 * MB);
    _Float16* W2l   = (_Float16*)(ws + 15 * MB);
    _Float16* W3th  = (_Float16*)(ws + 17 * MB);
    _Float16* W3tl  = (_Float16*)(ws + 19 * MB);
    _Float16* Mph   = (_Float16*)(ws + 21 * MB);
    _Float16* Mpl   = (_Float16*)(ws + 23 * MB);
    _Float16* Ath   = (_Float16*)(ws + 25 * MB);
    _Float16* Atl   = (_Float16*)(ws + 27 * MB);
    _Float16* W23th = (_Float16*)(ws + 29 * MB);
    _Float16* W23tl = (_Float16*)(ws + 31 * MB);
    _Float16* Th    = (_Float16*)(ws + 33 * MB);
    _Float16* Tl    = (_Float16*)(ws + 35 * MB);
    float*    Hm    = (float*)(ws + 37 * MB);
    float*    Pp    = (float*)(ws + 41 * MB);   // 8 MB (S2 partials)

    const float* W1 = Ws;
    const float* W2 = Ws + 1024 * 1024;
    const float* W3 = Ws + 2 * 1024 * 1024;
    const float* b1 = bsv;
    const float* b2 = bsv + 1024;
    const float* b3 = bsv + 2048;

    // 1: weight splits + zero Mcnt
    prepW<<<dim3(1024, 5), 256, 0, stream>>>(emb, W1, W2, W3, Mcnt,
        Eh, El, W1th, W1tl, W2h, W2l, W3th, W3tl);

    // 2: S1ab GEMMs overlapped with extract (role on fastest grid dim)
    GemmDesc dS1a = {Eh, El, W1th, W1tl, nullptr, nullptr, nullptr, Ath, Atl};
    GemmDesc dS1b = {W2h, W2l, W3th, W3tl, nullptr, nullptr, nullptr, W23th, W23tl};
    gemm_s1_extract<<<dim3(20, 16, 2), 256, 0, stream>>>(dS1a, dS1b, x, idx, Mcnt);

    // 3: M' from U (+counts from diag)
    prepM4<<<256, 256, 0, stream>>>(Mcnt, Mph, Mpl);

    // 4: S2 (k-split 2): Pp[z] = partial of M' @ A
    gemm_ks2_f32<<<dim3(16, 16, 2), 256, 0, stream>>>(Mph, Mpl, Ath, Atl, Pp);

    // 5: combineT (T = split(P0+P1)) + both beta vecmats
    combineT<<<dim3(1024, 3), 256, 0, stream>>>(Pp, Th, Tl,
        W23th, W23tl, b1, beta1p, W3th, W3tl, b2, beta2);

    // 6: S3: H = T @ W23 (f32 out, full-K -> single gather matrix)
    GemmDesc dS3 = {Th, Tl, W23th, W23tl, Hm, nullptr, nullptr, nullptr, nullptr};
    gemm_split<<<dim3(16, 16, 1), 256, 0, stream>>>(dS3, dS3);

    // 7: gather from single L2-resident H
    final_out<<<N_ROWS, 256, 0, stream>>>(Hm, idx, Mcnt, beta1p, beta2, b3, out);
}

// Round 19
// 113.673 us; speedup vs baseline: 1.0306x; 1.0306x over previous
//
#include <hip/hip_runtime.h>

#define N_ROWS 8192
#define IN_DIM 1024
#define KF     8

typedef _Float16 half8 __attribute__((ext_vector_type(8)));
typedef _Float16 half4 __attribute__((ext_vector_type(4)));
typedef float    floatx4 __attribute__((ext_vector_type(4)));
typedef float    floatx16 __attribute__((ext_vector_type(16)));

__device__ __forceinline__ half8 ld_half8(const _Float16* p) {
    int4 t = *(const int4*)p;
    return __builtin_bit_cast(half8, t);
}
__device__ __forceinline__ void fsplit(float v, _Float16& h, _Float16& l) {
    _Float16 x = (_Float16)v;
    h = x;
    l = (_Float16)((v - (float)x) * 2048.0f);
}
__device__ __forceinline__ void gload16(const void* g, void* l) {
    __builtin_amdgcn_global_load_lds(
        (const __attribute__((address_space(1))) void*)g,
        (__attribute__((address_space(3))) void*)l,
        16, 0, 0);
}

// ---------------------------------------------------------------------------
__global__ void zero_ws(float* __restrict__ Mcnt) {
    size_t i = ((size_t)blockIdx.x * 256 + threadIdx.x) << 2;
    floatx4 z = {0.f, 0.f, 0.f, 0.f};
    *(floatx4*)&Mcnt[i] = z;
}

// ---------------------------------------------------------------------------
// fused_pre: role = blockIdx.y
//  0: extract idx + upper-tri pair atomics (2048 blocks) -- atomic-bound
//  1: split E   2: split W2   (1024 blocks)              -- BW-bound
//  3: transp-split W1   4: transp-split W3 (256 blocks)  -- BW-bound
__global__ __launch_bounds__(256) void fused_pre(
        const int* __restrict__ x, int* __restrict__ idx, float* __restrict__ M,
        const float* __restrict__ emb, const float* __restrict__ W1,
        const float* __restrict__ W2, const float* __restrict__ W3,
        _Float16* __restrict__ Eh, _Float16* __restrict__ El,
        _Float16* __restrict__ W1th, _Float16* __restrict__ W1tl,
        _Float16* __restrict__ W2h, _Float16* __restrict__ W2l,
        _Float16* __restrict__ W3th, _Float16* __restrict__ W3tl) {
    const int role = blockIdx.y;
    const int bx   = blockIdx.x;

    if (role == 0) {           // extract_build (proven)
        const int wv   = threadIdx.x >> 6;
        const int r    = bx * 4 + wv;
        const int lane = threadIdx.x & 63;
        const int* row = x + (size_t)r * IN_DIM;

        __shared__ int cols[4][KF];

        int vals[16];
        #pragma unroll
        for (int j = 0; j < 4; ++j) {
            int4 v = ((const int4*)row)[lane * 4 + j];
            vals[j * 4 + 0] = v.x;
            vals[j * 4 + 1] = v.y;
            vals[j * 4 + 2] = v.z;
            vals[j * 4 + 3] = v.w;
        }
        int c = 0;
        #pragma unroll
        for (int j = 0; j < 16; ++j) c += (vals[j] != 0);

        int s = c;
        #pragma unroll
        for (int o = 1; o < 64; o <<= 1) {
            int t = __shfl_up(s, o, 64);
            if (lane >= o) s += t;
        }
        int pos = s - c;

        #pragma unroll
        for (int j = 0; j < 16; ++j) {
            if (vals[j] != 0) {
                int col = lane * 16 + j;
                if (pos < KF) {
                    idx[r * KF + pos] = col;
                    cols[wv][pos] = col;
                }
                pos++;
            }
        }
        __syncthreads();
        int i = lane >> 3, j = lane & 7;
        if (i <= j) {
            int ci = cols[wv][i];
            int cj = cols[wv][j];
            atomicAdd(&M[ci * IN_DIM + cj], 1.0f);
        }
        return;
    }

    const int task = role - 1;
    if (task <= 1) {           // natural split (proven)
        if (bx >= 1024) return;
        const float* S = task ? W2 : emb;
        _Float16* Hp = task ? W2h : Eh;
        _Float16* Lp = task ? W2l : El;
        size_t i = ((size_t)bx * 256 + threadIdx.x) << 2;
        float4 v = *(const float4*)&S[i];
        float vv[4] = {v.x, v.y, v.z, v.w};
        half4 h, l;
        #pragma unroll
        for (int j = 0; j < 4; ++j) { _Float16 hh, ll; fsplit(vv[j], hh, ll); h[j] = hh; l[j] = ll; }
        *(int2*)&Hp[i] = __builtin_bit_cast(int2, h);
        *(int2*)&Lp[i] = __builtin_bit_cast(int2, l);
        return;
    }
    if (bx >= 256) return;     // transposed split (proven)
    const float* S = (task == 3) ? W3 : W1;
    _Float16* Hp = (task == 3) ? W3th : W1th;
    _Float16* Lp = (task == 3) ? W3tl : W1tl;
    __shared__ float sh[64][65];
    const int r0 = (bx >> 4) << 6, c0 = (bx & 15) << 6;
    #pragma unroll
    for (int it = 0; it < 4; ++it) {
        int r = (threadIdx.x >> 4) + (it << 4);
        int c = (threadIdx.x & 15) << 2;
        float4 v = *(const float4*)&S[(size_t)(r0 + r) * 1024 + c0 + c];
        sh[r][c] = v.x; sh[r][c + 1] = v.y; sh[r][c + 2] = v.z; sh[r][c + 3] = v.w;
    }
    __syncthreads();
    int nl = threadIdx.x >> 2;
    #pragma unroll
    for (int cc = 0; cc < 2; ++cc) {
        int kq = ((threadIdx.x & 3) << 4) + (cc << 3);
        half8 h, l;
        #pragma unroll
        for (int j = 0; j < 8; ++j) {
            _Float16 hh, ll;
            fsplit(sh[kq + j][nl], hh, ll);
            h[j] = hh; l[j] = ll;
        }
        *(int4*)&Hp[(size_t)(c0 + nl) * 1024 + r0 + kq] = __builtin_bit_cast(int4, h);
        *(int4*)&Lp[(size_t)(c0 + nl) * 1024 + r0 + kq] = __builtin_bit_cast(int4, l);
    }
}

// ---------------------------------------------------------------------------
// prepM4: M' = diag(wG)*(U+U^T)*diag(d) + diag(wC), split; counts = diag(U)
__global__ __launch_bounds__(256) void prepM4(const float* __restrict__ Mc,
                                              _Float16* __restrict__ Mph,
                                              _Float16* __restrict__ Mpl) {
    const int bx = blockIdx.x;
    const int i0 = (bx >> 4) << 6;
    const int j0 = (bx & 15) << 6;
    __shared__ float tU[64][65];
    __shared__ float ddi[64], ddj[64];
    #pragma unroll
    for (int it = 0; it < 4; ++it) {
        int r = (threadIdx.x >> 4) + (it << 4);
        int c = (threadIdx.x & 15) << 2;
        float4 v = *(const float4*)&Mc[(size_t)(j0 + r) * 1024 + i0 + c];
        tU[r][c] = v.x; tU[r][c + 1] = v.y; tU[r][c + 2] = v.z; tU[r][c + 3] = v.w;
    }
    if (threadIdx.x < 64) {
        int c = i0 + threadIdx.x;
        ddi[threadIdx.x] = rsqrtf(Mc[(size_t)c * 1025] + 1.0f);
    } else if (threadIdx.x < 128) {
        int t = threadIdx.x - 64;
        int c = j0 + t;
        ddj[t] = rsqrtf(Mc[(size_t)c * 1025] + 1.0f);
    }
    __syncthreads();

    const float s1 = 1.f / 3.f, s3 = 1.f / 27.f, s5 = 1.f / 243.f;
    const int ii = threadIdx.x >> 2;
    const int gi = i0 + ii;
    float dr = ddi[ii];
    float d2 = dr * dr;
    float wg = s3 * d2;
    float wc = dr * (s1 * d2 * d2 + s3 * d2 + s5);

    #pragma unroll
    for (int q = 0; q < 4; ++q) {
        int jj = ((threadIdx.x & 3) << 4) + (q << 2);
        size_t gidx = (size_t)gi * 1024 + j0 + jj;
        float4 un = *(const float4*)&Mc[gidx];
        float uv[4] = {un.x, un.y, un.z, un.w};
        half4 h, l;
        #pragma unroll
        for (int t = 0; t < 4; ++t) {
            int gj = j0 + jj + t;
            float m = (gi == gj) ? uv[t] : (uv[t] + tU[jj + t][ii]);
            float v = m * ddj[jj + t] * wg + ((gi == gj) ? wc : 0.f);
            _Float16 hh, ll;
            fsplit(v, hh, ll);
            h[t] = hh; l[t] = ll;
        }
        *(int2*)&Mph[gidx] = __builtin_bit_cast(int2, h);
        *(int2*)&Mpl[gidx] = __builtin_bit_cast(int2, l);
    }
}

// ---------------------------------------------------------------------------
// proven split-f16 MFMA GEMM: 64x64 tile, 4 waves, 32x32x16 frags, 3 chains.
struct GemmDesc {
    const _Float16 *Ah, *Al;
    const _Float16 *Bh, *Bl;
    float* Df;
    _Float16 *Dnh, *Dnl;
    _Float16 *Dth, *Dtl;
};

__global__ __launch_bounds__(256) void gemm_split(GemmDesc d0, GemmDesc d1)
{
    GemmDesc d = blockIdx.z ? d1 : d0;
    __shared__ _Float16 lds[2][4][64][64];

    const int tid  = threadIdx.x;
    const int lane = tid & 63;
    const int w    = tid >> 6;
    const int wm   = w >> 1, wn = w & 1;
    const int brow = blockIdx.y << 6;
    const int bcol = blockIdx.x << 6;

    const _Float16* gsrc = (w == 0) ? d.Ah : (w == 1) ? d.Al : (w == 2) ? d.Bh : d.Bl;
    const int rowbase = (w < 2) ? brow : bcol;
    const int swz = (((lane & 7) ^ ((lane >> 3) & 7)) << 3);
    const _Float16* gbase = gsrc + (size_t)(rowbase + (lane >> 3)) * 1024 + swz;

#define STAGE(kt_, buf_) do {                                              \
        _Float16* lb = &lds[buf_][w][0][0];                                \
        const _Float16* gb = gbase + ((kt_) << 6);                         \
        _Pragma("unroll")                                                  \
        for (int c = 0; c < 8; ++c)                                        \
            gload16(gb + ((size_t)(c << 3) << 10), lb + (c << 9));         \
    } while (0)

    const int l31  = lane & 31;
    const int kh   = lane >> 5;
    const int arow = (wm << 5) + l31;
    const int brw  = (wn << 5) + l31;
    const int r7   = l31 & 7;

    floatx16 acc0 = {};
    floatx16 acc1 = {};
    floatx16 acc2 = {};

    STAGE(0, 0);
    __syncthreads();

    int cur = 0;
    for (int kt = 0; kt < 16; ++kt) {
        if (kt < 15) STAGE(kt + 1, cur ^ 1);
        const _Float16* pa_h = &lds[cur][0][arow][0];
        const _Float16* pa_l = &lds[cur][1][arow][0];
        const _Float16* pb_h = &lds[cur][2][brw][0];
        const _Float16* pb_l = &lds[cur][3][brw][0];
        #pragma unroll
        for (int kc = 0; kc < 4; ++kc) {
            int ca = ((((kc << 1) | kh) ^ r7) << 3);
            half8 ah = ld_half8(pa_h + ca);
            half8 al = ld_half8(pa_l + ca);
            half8 bh = ld_half8(pb_h + ca);
            half8 bl = ld_half8(pb_l + ca);
            acc0 = __builtin_amdgcn_mfma_f32_32x32x16_f16(ah, bh, acc0, 0, 0, 0);
            acc1 = __builtin_amdgcn_mfma_f32_32x32x16_f16(ah, bl, acc1, 0, 0, 0);
            acc2 = __builtin_amdgcn_mfma_f32_32x32x16_f16(al, bh, acc2, 0, 0, 0);
        }
        if (kt < 15) {
            __syncthreads();
            cur ^= 1;
        }
    }
#undef STAGE

    const float is = 1.0f / 2048.0f;
    const int grow = brow + (wm << 5) + (kh << 2);
    const int gcol = bcol + (wn << 5) + l31;

    if (d.Df) {
        #pragma unroll
        for (int r = 0; r < 16; ++r) {
            int row = grow + (r & 3) + ((r >> 2) << 3);
            d.Df[(size_t)row * 1024 + gcol] = acc0[r] + (acc1[r] + acc2[r]) * is;
        }
    }
    if (d.Dnh) {
        #pragma unroll
        for (int r = 0; r < 16; ++r) {
            int row = grow + (r & 3) + ((r >> 2) << 3);
            _Float16 h, l;
            fsplit(acc0[r] + (acc1[r] + acc2[r]) * is, h, l);
            d.Dnh[(size_t)row * 1024 + gcol] = h;
            d.Dnl[(size_t)row * 1024 + gcol] = l;
        }
    }
    if (d.Dth) {
        #pragma unroll
        for (int g = 0; g < 4; ++g) {
            half4 hv, lv;
            #pragma unroll
            for (int j = 0; j < 4; ++j) {
                int r = (g << 2) + j;
                _Float16 h, l;
                fsplit(acc0[r] + (acc1[r] + acc2[r]) * is, h, l);
                hv[j] = h; lv[j] = l;
            }
            int row = grow + (g << 3);
            *(int2*)&d.Dth[(size_t)gcol * 1024 + row] = __builtin_bit_cast(int2, hv);
            *(int2*)&d.Dtl[(size_t)gcol * 1024 + row] = __builtin_bit_cast(int2, lv);
        }
    }
}

// ---------------------------------------------------------------------------
// k-split-2 GEMM, f32 partials: grid (16,16,2), z = K-half. (proven, R15)
__global__ __launch_bounds__(256) void gemm_ks2_f32(
        const _Float16* __restrict__ Ah, const _Float16* __restrict__ Al,
        const _Float16* __restrict__ Bh, const _Float16* __restrict__ Bl,
        float* __restrict__ Pp)
{
    __shared__ _Float16 lds[2][4][64][64];

    const int tid  = threadIdx.x;
    const int lane = tid & 63;
    const int w    = tid >> 6;
    const int wm   = w >> 1, wn = w & 1;
    const int brow = blockIdx.y << 6;
    const int bcol = blockIdx.x << 6;
    const int kbeg = blockIdx.z << 9;

    const _Float16* gsrc = (w == 0) ? Ah : (w == 1) ? Al : (w == 2) ? Bh : Bl;
    const int rowbase = (w < 2) ? brow : bcol;
    const int swz = (((lane & 7) ^ ((lane >> 3) & 7)) << 3);
    const _Float16* gbase = gsrc + (size_t)(rowbase + (lane >> 3)) * 1024 + kbeg + swz;

#define STAGE(kt_, buf_) do {                                              \
        _Float16* lb = &lds[buf_][w][0][0];                                \
        const _Float16* gb = gbase + ((kt_) << 6);                         \
        _Pragma("unroll")                                                  \
        for (int c = 0; c < 8; ++c)                                        \
            gload16(gb + ((size_t)(c << 3) << 10), lb + (c << 9));         \
    } while (0)

    const int l31  = lane & 31;
    const int kh   = lane >> 5;
    const int arow = (wm << 5) + l31;
    const int brw  = (wn << 5) + l31;
    const int r7   = l31 & 7;

    floatx16 acc0 = {};
    floatx16 acc1 = {};
    floatx16 acc2 = {};

    STAGE(0, 0);
    __syncthreads();

    int cur = 0;
    for (int kt = 0; kt < 8; ++kt) {
        if (kt < 7) STAGE(kt + 1, cur ^ 1);
        const _Float16* pa_h = &lds[cur][0][arow][0];
        const _Float16* pa_l = &lds[cur][1][arow][0];
        const _Float16* pb_h = &lds[cur][2][brw][0];
        const _Float16* pb_l = &lds[cur][3][brw][0];
        #pragma unroll
        for (int kc = 0; kc < 4; ++kc) {
            int ca = ((((kc << 1) | kh) ^ r7) << 3);
            half8 ah = ld_half8(pa_h + ca);
            half8 al = ld_half8(pa_l + ca);
            half8 bh = ld_half8(pb_h + ca);
            half8 bl = ld_half8(pb_l + ca);
            acc0 = __builtin_amdgcn_mfma_f32_32x32x16_f16(ah, bh, acc0, 0, 0, 0);
            acc1 = __builtin_amdgcn_mfma_f32_32x32x16_f16(ah, bl, acc1, 0, 0, 0);
            acc2 = __builtin_amdgcn_mfma_f32_32x32x16_f16(al, bh, acc2, 0, 0, 0);
        }
        if (kt < 7) {
            __syncthreads();
            cur ^= 1;
        }
    }
#undef STAGE

    const float is = 1.0f / 2048.0f;
    const int grow = brow + (wm << 5) + (kh << 2);
    const int gcol = bcol + (wn << 5) + l31;
    float* Pt = Pp + ((size_t)blockIdx.z << 20);
    #pragma unroll
    for (int r = 0; r < 16; ++r) {
        int row = grow + (r & 3) + ((r >> 2) << 3);
        Pt[(size_t)row * 1024 + gcol] = acc0[r] + (acc1[r] + acc2[r]) * is;
    }
}

// ---------------------------------------------------------------------------
// combineT: y=0 -> T = split(P0+P1); y=1 -> beta1p = b1@W23; y=2 -> beta2 = b2@W3
__global__ __launch_bounds__(256) void combineT(
        const float* __restrict__ Pp,
        _Float16* __restrict__ Th, _Float16* __restrict__ Tl,
        const _Float16* __restrict__ W23th, const _Float16* __restrict__ W23tl,
        const float* __restrict__ b1, float* __restrict__ beta1p,
        const _Float16* __restrict__ W3th, const _Float16* __restrict__ W3tl,
        const float* __restrict__ b2, float* __restrict__ beta2) {
    if (blockIdx.y == 0) {
        size_t i = ((size_t)blockIdx.x * 256 + threadIdx.x) << 2;
        float4 a = *(const float4*)&Pp[i];
        float4 b = *(const float4*)&Pp[(1 << 20) + i];
        float vv[4] = {a.x + b.x, a.y + b.y, a.z + b.z, a.w + b.w};
        half4 h, l;
        #pragma unroll
        for (int j = 0; j < 4; ++j) { _Float16 hh, ll; fsplit(vv[j], hh, ll); h[j] = hh; l[j] = ll; }
        *(int2*)&Th[i] = __builtin_bit_cast(int2, h);
        *(int2*)&Tl[i] = __builtin_bit_cast(int2, l);
        return;
    }
    const int which = blockIdx.y - 1;
    const _Float16* Wh = which ? W3th : W23th;
    const _Float16* Wl = which ? W3tl : W23tl;
    const float*    vv = which ? b2 : b1;
    float*          yy = which ? beta2 : beta1p;
    const float is = 1.0f / 2048.0f;
    int n  = blockIdx.x;
    int k0 = threadIdx.x << 2;
    int2 th = *(const int2*)&Wh[(size_t)n * 1024 + k0];
    int2 tl = *(const int2*)&Wl[(size_t)n * 1024 + k0];
    half4 h = __builtin_bit_cast(half4, th);
    half4 l = __builtin_bit_cast(half4, tl);
    float4 b = *(const float4*)&vv[k0];
    float acc = ((float)h[0] + (float)l[0] * is) * b.x
              + ((float)h[1] + (float)l[1] * is) * b.y
              + ((float)h[2] + (float)l[2] * is) * b.z
              + ((float)h[3] + (float)l[3] * is) * b.w;
    #pragma unroll
    for (int o = 1; o < 64; o <<= 1) acc += __shfl_xor(acc, o, 64);
    __shared__ float red[4];
    if ((threadIdx.x & 63) == 0) red[threadIdx.x >> 6] = acc;
    __syncthreads();
    if (threadIdx.x == 0) yy[n] = red[0] + red[1] + red[2] + red[3];
}

// ---------------------------------------------------------------------------
// combineH: Hm = P0 + P1 (streaming, 1024 blocks)
__global__ void combineH(const float* __restrict__ Pp3, float* __restrict__ Hm) {
    size_t i = ((size_t)blockIdx.x * 256 + threadIdx.x) << 2;
    float4 a = *(const float4*)&Pp3[i];
    float4 b = *(const float4*)&Pp3[(1 << 20) + i];
    floatx4 o = {a.x + b.x, a.y + b.y, a.z + b.z, a.w + b.w};
    *(floatx4*)&Hm[i] = o;
}

// ---------------------------------------------------------------------------
// out[r] = sum_i H[c_i] + g1*beta1p + g2*beta2 + b3 ; counts from diag(U)
__global__ __launch_bounds__(256) void final_out(const float* __restrict__ H,
                                                 const int* __restrict__ idx,
                                                 const float* __restrict__ Mc,
                                                 const float* __restrict__ beta1p,
                                                 const float* __restrict__ beta2,
                                                 const float* __restrict__ b3,
                                                 float* __restrict__ out) {
    const int r = blockIdx.x;
    __shared__ int   sc[KF];
    __shared__ float sd[KF];
    if (threadIdx.x < KF) {
        int c = idx[r * KF + threadIdx.x];
        sc[threadIdx.x] = c;
        sd[threadIdx.x] = rsqrtf(Mc[(size_t)c * 1025] + 1.0f);
    }
    __syncthreads();

    const float s1 = 1.f / 3.f, s2 = 1.f / 9.f, s3 = 1.f / 27.f, s4 = 1.f / 81.f;

    float p = 0.f, q = 0.f, sum2 = 0.f;
    #pragma unroll
    for (int i = 0; i < KF; ++i) {
        float dd = sd[i];
        p += dd;
        sum2 += dd * dd;
        q += dd * dd * dd;
    }
    float u  = (float)KF - sum2;
    float g1 = s2 * u + s1 * q + s3 * p + s4;
    float g2 = s1 * p + s2;

    int j = threadIdx.x << 2;
    float4 bb1 = *(const float4*)&beta1p[j];
    float4 bb2 = *(const float4*)&beta2[j];
    float4 b3v = *(const float4*)&b3[j];
    floatx4 acc;
    acc.x = g1 * bb1.x + g2 * bb2.x + b3v.x;
    acc.y = g1 * bb1.y + g2 * bb2.y + b3v.y;
    acc.z = g1 * bb1.z + g2 * bb2.z + b3v.z;
    acc.w = g1 * bb1.w + g2 * bb2.w + b3v.w;

    #pragma unroll
    for (int i = 0; i < KF; ++i) {
        float4 h = *(const float4*)&H[(size_t)sc[i] * 1024 + j];
        acc.x += h.x;
        acc.y += h.y;
        acc.z += h.z;
        acc.w += h.w;
    }
    __builtin_nontemporal_store(acc, (floatx4*)&out[(size_t)r * 1024 + j]);
}

// ---------------------------------------------------------------------------
extern "C" void kernel_launch(void* const* d_in, const int* in_sizes, int n_in,
                              void* d_out, int out_size, void* d_ws, size_t ws_size,
                              hipStream_t stream) {
    const int*   x   = (const int*)d_in[0];
    const float* emb = (const float*)d_in[1];
    const float* Ws  = (const float*)d_in[2];
    const float* bsv = (const float*)d_in[3];
    float* out = (float*)d_out;

    char* ws = (char*)d_ws;
    const size_t MB = 1 << 20;
    int*   idx    = (int*)(ws);
    float* beta1p = (float*)(ws + 0x44000);
    float* beta2  = (float*)(ws + 0x45000);
    float* Mcnt   = (float*)(ws + 1 * MB);
    _Float16* Eh    = (_Float16*)(ws + 5 * MB);
    _Float16* El    = (_Float16*)(ws + 7 * MB);
    _Float16* W1th  = (_Float16*)(ws + 9 * MB);
    _Float16* W1tl  = (_Float16*)(ws + 11 * MB);
    _Float16* W2h   = (_Float16*)(ws + 13 * MB);
    _Float16* W2l   = (_Float16*)(ws + 15 * MB);
    _Float16* W3th  = (_Float16*)(ws + 17 * MB);
    _Float16* W3tl  = (_Float16*)(ws + 19 * MB);
    _Float16* Mph   = (_Float16*)(ws + 21 * MB);
    _Float16* Mpl   = (_Float16*)(ws + 23 * MB);
    _Float16* Ath   = (_Float16*)(ws + 25 * MB);
    _Float16* Atl   = (_Float16*)(ws + 27 * MB);
    _Float16* W23th = (_Float16*)(ws + 29 * MB);
    _Float16* W23tl = (_Float16*)(ws + 31 * MB);
    _Float16* Th    = (_Float16*)(ws + 33 * MB);
    _Float16* Tl    = (_Float16*)(ws + 35 * MB);
    float*    Hm    = (float*)(ws + 37 * MB);
    float*    Pp    = (float*)(ws + 41 * MB);   // 8 MB (S2 partials)
    float*    Pp3   = (float*)(ws + 49 * MB);   // 8 MB (S3 partials)

    const float* W1 = Ws;
    const float* W2 = Ws + 1024 * 1024;
    const float* W3 = Ws + 2 * 1024 * 1024;
    const float* b1 = bsv;
    const float* b2 = bsv + 1024;
    const float* b3 = bsv + 2048;

    zero_ws<<<1024, 256, 0, stream>>>(Mcnt);

    // extract (atomic-bound) overlapped with all weight splits (BW-bound)
    fused_pre<<<dim3(2048, 5), 256, 0, stream>>>(x, idx, Mcnt, emb, W1, W2, W3,
        Eh, El, W1th, W1tl, W2h, W2l, W3th, W3tl);

    prepM4<<<256, 256, 0, stream>>>(Mcnt, Mph, Mpl);

    // S1a: At = (E @ W1)^T ; S1b: W23t = (W2 @ W3)^T
    GemmDesc dS1a = {Eh, El, W1th, W1tl, nullptr, nullptr, nullptr, Ath, Atl};
    GemmDesc dS1b = {W2h, W2l, W3th, W3tl, nullptr, nullptr, nullptr, W23th, W23tl};
    gemm_split<<<dim3(16, 16, 2), 256, 0, stream>>>(dS1a, dS1b);

    // S2 (k-split 2): Pp[z] = partial of M' @ A
    gemm_ks2_f32<<<dim3(16, 16, 2), 256, 0, stream>>>(Mph, Mpl, Ath, Atl, Pp);

    // combineT (T = split(P0+P1)) + both beta vecmats
    combineT<<<dim3(1024, 3), 256, 0, stream>>>(Pp, Th, Tl,
        W23th, W23tl, b1, beta1p, W3th, W3tl, b2, beta2);

    // S3 (k-split 2): Pp3[z] = partial of T @ W23
    gemm_ks2_f32<<<dim3(16, 16, 2), 256, 0, stream>>>(Th, Tl, W23th, W23tl, Pp3);

    // combine partials -> single L2-resident H (R16 lesson: never gather partials)
    combineH<<<1024, 256, 0, stream>>>(Pp3, Hm);

    // gather from single H
    final_out<<<N_ROWS, 256, 0, stream>>>(Hm, idx, Mcnt, beta1p, beta2, b3, out);
}